// Round 4
// baseline (6974.034 us; speedup 1.0000x reference)
//
#include <hip/hip_runtime.h>

#define NNODES 60000
#define NPAD   60032
#define NBLK   469      // NPAD/128
#define NEDGES 150000
#define NGRAPH 2048
#define DIM    512
#define NLAYER 5

typedef unsigned short u16;
typedef unsigned int   u32;
typedef __attribute__((ext_vector_type(8))) short s16x8;
typedef __attribute__((ext_vector_type(4))) float f32x4;

__device__ __forceinline__ float b2f(u16 u){ u32 x=(u32)u<<16; return __builtin_bit_cast(float,x); }
__device__ __forceinline__ u16 f2b(float f){ u32 x=__builtin_bit_cast(u32,f); x += 0x7FFFu + ((x>>16)&1u); return (u16)(x>>16); }

// ---------------- transpose fp32 KxN -> bf16 NxK, [hi|lo] row-concat (stride ld) ----------------
__global__ void transpose_bt(const float* __restrict__ W, u16* __restrict__ Wt,
                             int K, int N, int ld, int wantLo){
  __shared__ float tile[32][33];
  int bx=blockIdx.x*32, by=blockIdx.y*32;
  int tx=threadIdx.x&31, ty=threadIdx.x>>5;
  for(int i=ty;i<32;i+=8) tile[i][tx]=W[(size_t)(by+i)*N + bx+tx];
  __syncthreads();
  for(int i=ty;i<32;i+=8){
    float v=tile[tx][i];
    u16 hi=f2b(v);
    size_t o=(size_t)(bx+i)*ld + by+tx;
    Wt[o]=hi;
    if(wantLo) Wt[o+K]=f2b(v-b2f(hi));
  }
}

// ---------------- dense K=40 -> 512, relu, bf16 out (hi plane + optional lo plane) ----------------
__global__ void dense40(const float* __restrict__ X, const float* __restrict__ W,
                        const float* __restrict__ b, u16* __restrict__ Yh,
                        u16* __restrict__ Yl, int ldy, int M, int Mpad){
  __shared__ float xs[64];
  int t=threadIdx.x;
  int c0=2*t;
  float w0[40], w1[40];
  #pragma unroll
  for(int k=0;k<40;++k){ w0[k]=W[k*DIM+c0]; w1[k]=W[k*DIM+c0+1]; }
  float bb0=b[c0], bb1=b[c0+1];
  for(int m=blockIdx.x;m<Mpad;m+=gridDim.x){
    size_t o=(size_t)m*ldy+c0;
    if(m<M){
      if(t<40) xs[t]=X[m*40+t];
      __syncthreads();
      float a0=bb0, a1=bb1;
      #pragma unroll
      for(int k=0;k<40;++k){ float xv=xs[k]; a0+=xv*w0[k]; a1+=xv*w1[k]; }
      a0=fmaxf(a0,0.f); a1=fmaxf(a1,0.f);
      u16 h0=f2b(a0), h1=f2b(a1);
      *(u32*)&Yh[o]=(u32)h0|((u32)h1<<16);
      if(Yl) *(u32*)&Yl[o]=(u32)f2b(a0-b2f(h0))|((u32)f2b(a1-b2f(h1))<<16);
      __syncthreads();
    } else {
      *(u32*)&Yh[o]=0u;
      if(Yl) *(u32*)&Yl[o]=0u;
    }
  }
}

// ---------------- CSR build ----------------
__global__ void hist_kernel(const int* __restrict__ idx, int* __restrict__ cnt, int n){
  int i=blockIdx.x*256+threadIdx.x;
  if(i<n) atomicAdd(&cnt[idx[i]],1);
}

// three-kernel parallel exclusive scan (n <= 256*256)
__global__ void block_sums(const int* __restrict__ in, int* __restrict__ psum, int n){
  __shared__ int s[256];
  int i=blockIdx.x*256+threadIdx.x;
  s[threadIdx.x]=(i<n)?in[i]:0;
  __syncthreads();
  for(int o=128;o;o>>=1){ if(threadIdx.x<o) s[threadIdx.x]+=s[threadIdx.x+o]; __syncthreads(); }
  if(threadIdx.x==0) psum[blockIdx.x]=s[0];
}
__global__ void scan_partials(int* __restrict__ psum, int nb){
  __shared__ int s[256];
  int t=threadIdx.x;
  s[t]=(t<nb)?psum[t]:0;
  __syncthreads();
  for(int o=1;o<256;o<<=1){
    int v=(t>=o)?s[t-o]:0;
    __syncthreads();
    s[t]+=v;
    __syncthreads();
  }
  if(t<nb) psum[t]= t? s[t-1]:0;
}
__global__ void scan_write(const int* __restrict__ in, const int* __restrict__ psum,
                           int* __restrict__ out, int n){
  __shared__ int s[256];
  int t=threadIdx.x;
  int i=blockIdx.x*256+t;
  s[t]=(i<n)?in[i]:0;
  __syncthreads();
  for(int o=1;o<256;o<<=1){
    int v=(t>=o)?s[t-o]:0;
    __syncthreads();
    s[t]+=v;
    __syncthreads();
  }
  if(i<n) out[i+1]=psum[blockIdx.x]+s[t];
  if(i==0) out[0]=0;
}

__global__ void scatter_edges(const int* __restrict__ eidx, const int* __restrict__ eattr,
                              const int* __restrict__ rowptr, int* __restrict__ cnt,
                              u32* __restrict__ es_pk){
  int e=blockIdx.x*256+threadIdx.x;
  if(e>=NEDGES) return;
  int s=eidx[e], d=eidx[NEDGES+e];
  int pos=rowptr[d]+atomicAdd(&cnt[d],1);
  es_pk[pos]=(u32)s | ((u32)(eattr[2*e]*3+eattr[2*e+1])<<16);
}

__global__ void scatter_batch(const int* __restrict__ batch, const int* __restrict__ browptr,
                              int* __restrict__ bcnt, u16* __restrict__ bnodes){
  int n=blockIdx.x*256+threadIdx.x;
  if(n>=NNODES) return;
  int g=batch[n];
  int pos=browptr[g]+atomicAdd(&bcnt[g],1);
  bnodes[pos]=(u16)n;
}

// ---- aggregate rows [n0,n1): agg[.] = h[n]+self + sum_e(h[src]+emb); out [hi512|lo512] stride1024 ----
__global__ void agg_kernel(const u16* __restrict__ hh, const u16* __restrict__ hl,
    const int* __restrict__ rowptr, const u32* __restrict__ es_pk,
    const float* __restrict__ emb1, const float* __restrict__ emb2,
    u16* __restrict__ agg, int n0, int n1){
  __shared__ float combo[10][DIM];
  for(int i=threadIdx.x;i<10*DIM;i+=256){
    int c=i>>9, d=i&(DIM-1);
    int bt=(c<9)?(c/3):4, bd=(c<9)?(c%3):0;
    combo[c][d]=emb1[bt*DIM+d]+emb2[bd*DIM+d];
  }
  __syncthreads();
  int c0=2*threadIdx.x;
  for(int n=n0+blockIdx.x;n<n1;n+=gridDim.x){
    float a0,a1;
    if(n<NNODES){
      size_t ix=(size_t)n*DIM+c0;
      u32 hv=*(const u32*)&hh[ix];
      a0=b2f((u16)hv)+combo[9][c0];
      a1=b2f((u16)(hv>>16))+combo[9][c0+1];
      if(hl){ u32 lv=*(const u32*)&hl[ix]; a0+=b2f((u16)lv); a1+=b2f((u16)(lv>>16)); }
      int pe=rowptr[n+1];
      for(int p=rowptr[n];p<pe;++p){
        u32 pk=es_pk[p];
        int s=pk&0xFFFF, c=pk>>16;
        size_t sx=(size_t)s*DIM+c0;
        u32 sv=*(const u32*)&hh[sx];
        a0+=b2f((u16)sv)+combo[c][c0];
        a1+=b2f((u16)(sv>>16))+combo[c][c0+1];
        if(hl){ u32 lv=*(const u32*)&hl[sx]; a0+=b2f((u16)lv); a1+=b2f((u16)(lv>>16)); }
      }
    } else { a0=0.f; a1=0.f; }
    size_t o=(size_t)(n-n0)*1024+c0;
    u16 h0=f2b(a0), h1=f2b(a1);
    *(u32*)&agg[o]=(u32)h0|((u32)h1<<16);
    *(u32*)&agg[o+512]=(u32)f2b(a0-b2f(h0))|((u32)f2b(a1-b2f(h1))<<16);
  }
}

// ---- segment GEMM: C = act(sum_s A[:,ao_s:]*B[:,bo_s:]^T + bias); 32KB LDS, single plane ----
__global__ __launch_bounds__(256) void gemm_seg(
    const u16* __restrict__ A, int lda,
    const u16* __restrict__ B, int ldb,
    const float* __restrict__ bias,
    u16* __restrict__ Ch, u16* __restrict__ Cl, int ldc,
    int K, int nseg, int a1, int b1, int a2, int b2, int relu)
{
  __shared__ u16 As[128*64] __attribute__((aligned(16)));
  __shared__ u16 Bs[128*64] __attribute__((aligned(16)));
  int t=threadIdx.x, w=t>>6, l=t&63;
  size_t col0=(size_t)blockIdx.x*128, row0=(size_t)blockIdx.y*128;
  int wr=w>>1, wc=w&1;
  int lr=l&15, lk=(l>>4)*8;
  f32x4 acc[4][4]={};
  for(int s=0;s<nseg;++s){
    int ao = (s==0)?0:((s==1)?a1:a2);
    int bo = (s==0)?0:((s==1)?b1:b2);
    const u16* Ag=A+ao;
    const u16* Bg=B+bo;
    for(int k0=0;k0<K;k0+=64){
      #pragma unroll
      for(int i=0;i<4;++i){
        int c=i*256+t; int r=c>>3, c8=c&7;
        __builtin_amdgcn_global_load_lds(
          (const __attribute__((address_space(1))) void*)(Ag+(row0+r)*lda+k0+c8*8),
          (__attribute__((address_space(3))) void*)(As+(size_t)(i*256+(w<<6))*8), 16,0,0);
        __builtin_amdgcn_global_load_lds(
          (const __attribute__((address_space(1))) void*)(Bg+(col0+r)*ldb+k0+c8*8),
          (__attribute__((address_space(3))) void*)(Bs+(size_t)(i*256+(w<<6))*8), 16,0,0);
      }
      __syncthreads();
      #pragma unroll
      for(int kk=0;kk<2;++kk){
        s16x8 av[4],bv[4];
        #pragma unroll
        for(int m=0;m<4;++m) av[m]=*(const s16x8*)(As+(wr*64+m*16+lr)*64+kk*32+lk);
        #pragma unroll
        for(int n=0;n<4;++n) bv[n]=*(const s16x8*)(Bs+(wc*64+n*16+lr)*64+kk*32+lk);
        #pragma unroll
        for(int m=0;m<4;++m)
          #pragma unroll
          for(int n=0;n<4;++n)
            acc[m][n]=__builtin_amdgcn_mfma_f32_16x16x32_bf16(av[m],bv[n],acc[m][n],0,0,0);
      }
      __syncthreads();
    }
  }
  #pragma unroll
  for(int n=0;n<4;++n){
    int col=(int)col0+wc*64+n*16+lr;
    float bcol=bias[col];
    #pragma unroll
    for(int m=0;m<4;++m){
      int rowb=(int)row0+wr*64+m*16+((l>>4)*4);
      #pragma unroll
      for(int r=0;r<4;++r){
        float v=acc[m][n][r]+bcol;
        if(relu) v=fmaxf(v,0.f);
        size_t o=(size_t)(rowb+r)*ldc+col;
        u16 hi=f2b(v);
        Ch[o]=hi;
        if(Cl) Cl[o]=f2b(v-b2f(hi));
      }
    }
  }
}

// ---------------- BatchNorm ----------------
__global__ void bn_stats(const u16* __restrict__ h2h, const u16* __restrict__ h2l,
                         float* __restrict__ stats){
  int t=threadIdx.x, c0=2*t;
  int r0=blockIdx.x*64;
  int r1=r0+64; if(r1>NNODES) r1=NNODES;
  float s0=0,s1=0,q0=0,q1=0;
  for(int r=r0;r<r1;++r){
    size_t ix=(size_t)r*DIM+c0;
    u32 v=*(const u32*)&h2h[ix];
    float x=b2f((u16)v), y=b2f((u16)(v>>16));
    if(h2l){ u32 lv=*(const u32*)&h2l[ix]; x+=b2f((u16)lv); y+=b2f((u16)(lv>>16)); }
    s0+=x; q0+=x*x; s1+=y; q1+=y*y;
  }
  atomicAdd(&stats[c0],s0); atomicAdd(&stats[c0+1],s1);
  atomicAdd(&stats[DIM+c0],q0); atomicAdd(&stats[DIM+c0+1],q1);
}

__global__ void bn_finalize(float* __restrict__ stats, const float* __restrict__ gamma,
                            const float* __restrict__ beta){
  int d=threadIdx.x;
  float mu=stats[d]*(1.f/NNODES);
  float var=stats[DIM+d]*(1.f/NNODES)-mu*mu;
  float sc=gamma[d]*rsqrtf(var+1e-5f);
  stats[2*DIM+d]=sc;
  stats[3*DIM+d]=beta[d]-mu*sc;
}

__global__ void bn_apply(const u16* __restrict__ h2h, const u16* __restrict__ h2l,
    const float* __restrict__ stats, u16* __restrict__ hh, u16* __restrict__ hl, int relu){
  int idx=blockIdx.x*256+threadIdx.x;  // NNODES*64 threads, 8 elems each
  int d0=(idx&63)*8;
  size_t base=(size_t)idx*8;
  s16x8 v=*(const s16x8*)&h2h[base];
  s16x8 vl;
  if(h2l) vl=*(const s16x8*)&h2l[base];
  u16 oh[8], ol[8];
  #pragma unroll
  for(int j=0;j<8;++j){
    int d=d0+j;
    float x=b2f((u16)v[j]);
    if(h2l) x+=b2f((u16)vl[j]);
    x=x*stats[2*DIM+d]+stats[3*DIM+d];
    if(relu) x=fmaxf(x,0.f);
    u16 hi=f2b(x);
    oh[j]=hi; ol[j]=f2b(x-b2f(hi));
  }
  *(s16x8*)&hh[base]=*(const s16x8*)oh;
  if(hl) *(s16x8*)&hl[base]=*(const s16x8*)ol;
}

// ---------------- graph pooling (writes solute cols of z; [hi|lo] stride ldz) ----------------
__global__ void batch_reduce(const u16* __restrict__ hh, const u16* __restrict__ hl,
    const int* __restrict__ browptr, const u16* __restrict__ bnodes,
    u16* __restrict__ z, int ldz, int zLo){
  int g=blockIdx.x, t=threadIdx.x, c0=2*t;
  float a0=0,a1=0;
  int pe=browptr[g+1];
  for(int p=browptr[g];p<pe;++p){
    int n=bnodes[p];
    size_t ix=(size_t)n*DIM+c0;
    u32 v=*(const u32*)&hh[ix];
    a0+=b2f((u16)v); a1+=b2f((u16)(v>>16));
    if(hl){ u32 lv=*(const u32*)&hl[ix]; a0+=b2f((u16)lv); a1+=b2f((u16)(lv>>16)); }
  }
  size_t o=(size_t)g*ldz+c0;
  u16 h0=f2b(a0), h1=f2b(a1);
  *(u32*)&z[o]=(u32)h0|((u32)h1<<16);
  if(zLo) *(u32*)&z[o+1024]=(u32)f2b(a0-b2f(h0))|((u32)f2b(a1-b2f(h1))<<16);
}

// ---------------- last layer: dot(128) + bias ----------------
__global__ void last_kernel(const u16* __restrict__ z2, int ld, int zLo,
    const float* __restrict__ lw, const float* __restrict__ lb, float* __restrict__ out){
  int g=blockIdx.x*4+(threadIdx.x>>6), l=threadIdx.x&63;
  size_t b=(size_t)g*ld;
  float x0=b2f(z2[b+l]), x1=b2f(z2[b+64+l]);
  if(zLo){ x0+=b2f(z2[b+128+l]); x1+=b2f(z2[b+128+64+l]); }
  float a=x0*lw[l]+x1*lw[64+l];
  #pragma unroll
  for(int off=32;off;off>>=1) a+=__shfl_down(a,off,64);
  if(l==0) out[g]=a+lb[0];
}

extern "C" void kernel_launch(void* const* d_in, const int* in_sizes, int n_in,
                              void* d_out, int out_size, void* d_ws, size_t ws_size,
                              hipStream_t stream){
  (void)in_sizes; (void)n_in; (void)out_size;
  const float* solute_x =(const float*)d_in[0];
  const float* solvent_x=(const float*)d_in[1];
  const int*   eidx     =(const int*)d_in[2];
  const int*   eattr    =(const int*)d_in[3];
  const int*   batch    =(const int*)d_in[4];
  const float* xembW=(const float*)d_in[5];
  const float* xembB=(const float*)d_in[6];
  const float* m1W=(const float*)d_in[7];
  const float* m1b=(const float*)d_in[8];
  const float* m2W=(const float*)d_in[9];
  const float* m2b=(const float*)d_in[10];
  const float* ee1=(const float*)d_in[11];
  const float* ee2=(const float*)d_in[12];
  const float* gam=(const float*)d_in[13];
  const float* bet=(const float*)d_in[14];
  const float* sW1=(const float*)d_in[15];
  const float* sb1=(const float*)d_in[16];
  const float* sW2=(const float*)d_in[17];
  const float* sb2=(const float*)d_in[18];
  const float* oW0=(const float*)d_in[19];
  const float* ob0=(const float*)d_in[20];
  const float* oW1=(const float*)d_in[21];
  const float* ob1=(const float*)d_in[22];
  const float* oW2=(const float*)d_in[23];
  const float* ob2=(const float*)d_in[24];
  const float* lW =(const float*)d_in[25];
  const float* lb =(const float*)d_in[26];
  float* out=(float*)d_out;

  // ---- layout calculator (must mirror alloc order below) ----
  auto need=[&](int wL,int zL,int h2L,int hL,int chb)->size_t{
    size_t s=0; auto A=[&](size_t b){ s+=(b+255)&~(size_t)255; };
    A((size_t)NPAD*DIM*2); A((size_t)NPAD*DIM*2);               // h_hi, h2_hi
    if(hL)  A((size_t)NPAD*DIM*2);
    if(h2L) A((size_t)NPAD*DIM*2);
    A((size_t)NLAYER*1024*(512<<wL)*2); A((size_t)NLAYER*512*(1024<<wL)*2);
    A((size_t)512*(512<<wL)*2); A((size_t)512*(1024<<wL)*2);
    A((size_t)256*(512<<wL)*2); A((size_t)128*(256<<wL)*2);
    A((size_t)NGRAPH*(512<<zL)*2); A((size_t)NGRAPH*(1024<<zL)*2); A((size_t)NGRAPH*(512<<zL)*2);
    A((size_t)NGRAPH*(256<<zL)*2); A((size_t)NGRAPH*(128<<zL)*2);
    A(4*DIM*4);
    A((size_t)(NNODES+1)*4); A((size_t)NNODES*4); A((size_t)NEDGES*4);
    A((size_t)NGRAPH*4); A((size_t)(NGRAPH+1)*4); A((size_t)NGRAPH*4); A((size_t)NNODES*2);
    A((size_t)chb*128*1024*2); A((size_t)chb*128*2048*2);       // agg, t
    return s+4096;
  };
  if(need(0,0,0,0,1)>ws_size) return;   // cannot fit minimum: launch nothing (diagnostic)
  int wL = need(1,0,0,0,1)<=ws_size ? 1:0;
  int zL = need(wL,1,0,0,1)<=ws_size ? 1:0;
  int h2L= need(wL,zL,1,0,32)<=ws_size ? 1:0;
  int hL = need(wL,zL,h2L,1,32)<=ws_size ? 1:0;
  int chb=1;
  while(chb<NBLK && need(wL,zL,h2L,hL,chb+1)<=ws_size) ++chb;

  char* p=(char*)d_ws; size_t off=0;
  auto alloc=[&](size_t b)->void*{ void* q=p+off; off+=(b+255)&~(size_t)255; return q; };
  u16* h_hi  =(u16*)alloc((size_t)NPAD*DIM*2);
  u16* h2_hi =(u16*)alloc((size_t)NPAD*DIM*2);
  u16* h_lo  = hL ? (u16*)alloc((size_t)NPAD*DIM*2):0;
  u16* h2_lo = h2L? (u16*)alloc((size_t)NPAD*DIM*2):0;
  int ldW1=512<<wL, ldW2=1024<<wL, ldS2=512<<wL, ldO0=1024<<wL, ldO1=512<<wL, ldO2=256<<wL;
  u16* W1t =(u16*)alloc((size_t)NLAYER*1024*ldW1*2);
  u16* W2t =(u16*)alloc((size_t)NLAYER*512*ldW2*2);
  u16* sW2t=(u16*)alloc((size_t)512*ldS2*2);
  u16* oW0t=(u16*)alloc((size_t)512*ldO0*2);
  u16* oW1t=(u16*)alloc((size_t)256*ldO1*2);
  u16* oW2t=(u16*)alloc((size_t)128*ldO2*2);
  int ldS1=512<<zL, ldZ=1024<<zL, ldZ0=512<<zL, ldZ1=256<<zL, ldZ2=128<<zL;
  u16* s1 =(u16*)alloc((size_t)NGRAPH*ldS1*2);
  u16* z  =(u16*)alloc((size_t)NGRAPH*ldZ*2);
  u16* z0 =(u16*)alloc((size_t)NGRAPH*ldZ0*2);
  u16* z1 =(u16*)alloc((size_t)NGRAPH*ldZ1*2);
  u16* z2 =(u16*)alloc((size_t)NGRAPH*ldZ2*2);
  float* stats=(float*)alloc(4*DIM*4);
  int* rowptr =(int*)alloc((size_t)(NNODES+1)*4);
  int* degcnt =(int*)alloc((size_t)NNODES*4);
  u32* es_pk  =(u32*)alloc((size_t)NEDGES*4);
  int* bdeg   =(int*)alloc((size_t)NGRAPH*4);
  int* browptr=(int*)alloc((size_t)(NGRAPH+1)*4);
  int* bcnt   =(int*)alloc((size_t)NGRAPH*4);
  u16* bnodes =(u16*)alloc((size_t)NNODES*2);
  u16* agg_c  =(u16*)alloc((size_t)chb*128*1024*2);
  u16* t_c    =(u16*)alloc((size_t)chb*128*2048*2);

  // segment descriptors: s0=(0,0); s1,s2 per A/B lo availability
  auto segs=[&](int aLo,int bLo,int K,int& ns,int& A1,int& B1,int& A2,int& B2){
    ns=1; A1=B1=A2=B2=0;
    if(aLo){ A1=K; B1=0; ns++; }
    if(bLo){ if(ns==1){A1=0;B1=K;} else {A2=0;B2=K;} ns++; }
  };

  // ---- weight transposes ----
  for(int l=0;l<NLAYER;++l){
    transpose_bt<<<dim3(32,16),256,0,stream>>>(m1W+(size_t)l*512*1024, W1t+(size_t)l*1024*ldW1, 512,1024, ldW1, wL);
    transpose_bt<<<dim3(16,32),256,0,stream>>>(m2W+(size_t)l*1024*512, W2t+(size_t)l*512*ldW2, 1024,512, ldW2, wL);
  }
  transpose_bt<<<dim3(16,16),256,0,stream>>>(sW2, sW2t, 512,512, ldS2, wL);
  transpose_bt<<<dim3(16,32),256,0,stream>>>(oW0, oW0t, 1024,512, ldO0, wL);
  transpose_bt<<<dim3(8,16),256,0,stream>>>(oW1, oW1t, 512,256, ldO1, wL);
  transpose_bt<<<dim3(4,8),256,0,stream>>>(oW2, oW2t, 256,128, ldO2, wL);

  // ---- embed ----
  dense40<<<2048,256,0,stream>>>(solute_x, xembW, xembB, h_hi, h_lo, 512, NNODES, NPAD);

  // ---- edge CSR (parallel scan) ----
  hipMemsetAsync(degcnt,0,(size_t)NNODES*4,stream);
  hist_kernel<<<(NEDGES+255)/256,256,0,stream>>>(eidx+NEDGES, degcnt, NEDGES);
  {
    int nb=(NNODES+255)/256;   // 235
    block_sums<<<nb,256,0,stream>>>(degcnt, bcnt /*reuse as psum? too small*/, 0); // placeholder removed below
  }
  // NOTE: psum buffers: reuse stats tail? allocate small dedicated scratch from bdeg? use browptr? Use dedicated:
  // (we reuse 'bdeg' (2048 ints) as psum scratch for the node scan; it is re-zeroed later)
  {
    int nb=(NNODES+255)/256;
    block_sums<<<nb,256,0,stream>>>(degcnt, bdeg, NNODES);
    scan_partials<<<1,256,0,stream>>>(bdeg, nb);
    scan_write<<<nb,256,0,stream>>>(degcnt, bdeg, rowptr, NNODES);
  }
  hipMemsetAsync(degcnt,0,(size_t)NNODES*4,stream);
  scatter_edges<<<(NEDGES+255)/256,256,0,stream>>>(eidx, eattr, rowptr, degcnt, es_pk);

  // ---- batch CSR ----
  hipMemsetAsync(bdeg,0,(size_t)NGRAPH*4,stream);
  hist_kernel<<<(NNODES+255)/256,256,0,stream>>>(batch, bdeg, NNODES);
  {
    int nb=(NGRAPH+255)/256;   // 8
    block_sums<<<nb,256,0,stream>>>(bdeg, bcnt, NGRAPH);
    scan_partials<<<1,256,0,stream>>>(bcnt, nb);
    scan_write<<<nb,256,0,stream>>>(bdeg, bcnt, browptr, NGRAPH);
  }
  hipMemsetAsync(bcnt,0,(size_t)NGRAPH*4,stream);
  scatter_batch<<<(NNODES+255)/256,256,0,stream>>>(batch, browptr, bcnt, bnodes);

  // ---- GNN layers ----
  int ns1,a11,b11,a12,b12; segs(1,wL,512,ns1,a11,b11,a12,b12);     // gemm1: A=agg split, B=W1
  int ns2,a21,b21,a22,b22; segs(1,wL,1024,ns2,a21,b21,a22,b22);    // gemm2: A=t split, B=W2
  for(int l=0;l<NLAYER;++l){
    const float* e1=ee1+(size_t)l*6*DIM;
    const float* e2=ee2+(size_t)l*3*DIM;
    for(int b0=0;b0<NBLK;b0+=chb){
      int nb=NBLK-b0; if(nb>chb) nb=chb;
      int n0=b0*128, rows=nb*128;
      int g=rows<2048?rows:2048;
      agg_kernel<<<g,256,0,stream>>>(h_hi,h_lo, rowptr, es_pk, e1, e2, agg_c, n0, n0+rows);
      gemm_seg<<<dim3(8,nb),256,0,stream>>>(agg_c, 1024, W1t+(size_t)l*1024*ldW1, ldW1,
          m1b+(size_t)l*1024, t_c, t_c+1024, 2048, 512, ns1,a11,b11,a12,b12, 1);
      gemm_seg<<<dim3(4,nb),256,0,stream>>>(t_c, 2048, W2t+(size_t)l*512*ldW2, ldW2,
          m2b+(size_t)l*512, h2_hi+(size_t)n0*DIM, h2L? h2_lo+(size_t)n0*DIM:0, 512,
          1024, ns2,a21,b21,a22,b22, 0);
    }
    hipMemsetAsync(stats,0,2*DIM*4,stream);
    bn_stats<<<(NNODES+63)/64,256,0,stream>>>(h2_hi,h2_lo, stats);
    bn_finalize<<<1,512,0,stream>>>(stats, gam+(size_t)l*DIM, bet+(size_t)l*DIM);
    bn_apply<<<(NNODES*64)/256,256,0,stream>>>(h2_hi,h2_lo, stats, h_hi,h_lo, (l<NLAYER-1)?1:0);
  }

  // ---- pooling + solvent + readout ----
  batch_reduce<<<NGRAPH,256,0,stream>>>(h_hi,h_lo, browptr, bnodes, z, ldZ, zL);
  dense40<<<2048,256,0,stream>>>(solvent_x, sW1, sb1, s1, zL? s1+512:0, ldS1, NGRAPH, NGRAPH);
  int nsr,ar1,br1,ar2,br2;
  segs(zL,wL,512,nsr,ar1,br1,ar2,br2);
  gemm_seg<<<dim3(4,16),256,0,stream>>>(s1, ldS1, sW2t, ldS2, sb2,
      z+512, zL? z+1024+512:0, ldZ, 512, nsr,ar1,br1,ar2,br2, 0);
  segs(zL,wL,1024,nsr,ar1,br1,ar2,br2);
  gemm_seg<<<dim3(4,16),256,0,stream>>>(z, ldZ, oW0t, ldO0, ob0,
      z0, zL? z0+512:0, ldZ0, 1024, nsr,ar1,br1,ar2,br2, 1);
  segs(zL,wL,512,nsr,ar1,br1,ar2,br2);
  gemm_seg<<<dim3(2,16),256,0,stream>>>(z0, ldZ0, oW1t, ldO1, ob1,
      z1, zL? z1+256:0, ldZ1, 512, nsr,ar1,br1,ar2,br2, 1);
  segs(zL,wL,256,nsr,ar1,br1,ar2,br2);
  gemm_seg<<<dim3(1,16),256,0,stream>>>(z1, ldZ1, oW2t, ldO2, ob2,
      z2, zL? z2+128:0, ldZ2, 256, nsr,ar1,br1,ar2,br2, 1);
  last_kernel<<<NGRAPH/4,256,0,stream>>>(z2, ldZ2, zL, lW, lb, out);
}

// Round 5
// 1953.690 us; speedup vs baseline: 3.5697x; 3.5697x over previous
//
#include <hip/hip_runtime.h>

#define NNODES 60000
#define NPAD   60032
#define NBLK   469      // NPAD/128
#define NEDGES 150000
#define NGRAPH 2048
#define DIM    512
#define NLAYER 5

typedef unsigned short u16;
typedef unsigned int   u32;
typedef _Float16 f16;
typedef __attribute__((ext_vector_type(8))) _Float16 h8;
typedef __attribute__((ext_vector_type(8))) short s16x8;
typedef __attribute__((ext_vector_type(4))) float f32x4;

__device__ __forceinline__ float h2f(u16 u){ return (float)__builtin_bit_cast(f16,u); }
__device__ __forceinline__ u16 f2h(float f){ return __builtin_bit_cast(u16,(f16)f); }

// ---------------- transpose fp32 KxN -> fp16 NxK ----------------
__global__ void transpose_bt(const float* __restrict__ W, u16* __restrict__ Wt, int K, int N){
  __shared__ float tile[32][33];
  int bx=blockIdx.x*32, by=blockIdx.y*32;
  int tx=threadIdx.x&31, ty=threadIdx.x>>5;
  for(int i=ty;i<32;i+=8) tile[i][tx]=W[(size_t)(by+i)*N + bx+tx];
  __syncthreads();
  for(int i=ty;i<32;i+=8) Wt[(size_t)(bx+i)*K + by+tx]=f2h(tile[tx][i]);
}

// ---------------- dense K=40 -> 512, relu, fp16 out ----------------
__global__ void dense40(const float* __restrict__ X, const float* __restrict__ W,
                        const float* __restrict__ b, u16* __restrict__ Y, int M, int Mpad){
  __shared__ float xs[64];
  int t=threadIdx.x;
  int c0=2*t;
  float w0[40], w1[40];
  #pragma unroll
  for(int k=0;k<40;++k){ w0[k]=W[k*DIM+c0]; w1[k]=W[k*DIM+c0+1]; }
  float bb0=b[c0], bb1=b[c0+1];
  for(int m=blockIdx.x;m<Mpad;m+=gridDim.x){
    size_t o=(size_t)m*DIM+c0;
    if(m<M){
      if(t<40) xs[t]=X[m*40+t];
      __syncthreads();
      float a0=bb0, a1=bb1;
      #pragma unroll
      for(int k=0;k<40;++k){ float xv=xs[k]; a0+=xv*w0[k]; a1+=xv*w1[k]; }
      a0=fmaxf(a0,0.f); a1=fmaxf(a1,0.f);
      *(u32*)&Y[o]=(u32)f2h(a0)|((u32)f2h(a1)<<16);
      __syncthreads();
    } else {
      *(u32*)&Y[o]=0u;
    }
  }
}

// ---------------- CSR build ----------------
__global__ void hist_kernel(const int* __restrict__ idx, int* __restrict__ cnt, int n){
  int i=blockIdx.x*256+threadIdx.x;
  if(i<n) atomicAdd(&cnt[idx[i]],1);
}

__global__ void block_sums(const int* __restrict__ in, int* __restrict__ psum, int n){
  __shared__ int s[256];
  int i=blockIdx.x*256+threadIdx.x;
  s[threadIdx.x]=(i<n)?in[i]:0;
  __syncthreads();
  for(int o=128;o;o>>=1){ if(threadIdx.x<o) s[threadIdx.x]+=s[threadIdx.x+o]; __syncthreads(); }
  if(threadIdx.x==0) psum[blockIdx.x]=s[0];
}
__global__ void scan_partials(int* __restrict__ psum, int nb){
  __shared__ int s[256];
  int t=threadIdx.x;
  s[t]=(t<nb)?psum[t]:0;
  __syncthreads();
  for(int o=1;o<256;o<<=1){
    int v=(t>=o)?s[t-o]:0;
    __syncthreads();
    s[t]+=v;
    __syncthreads();
  }
  if(t<nb) psum[t]= t? s[t-1]:0;
}
__global__ void scan_write(const int* __restrict__ in, const int* __restrict__ psum,
                           int* __restrict__ out, int n){
  __shared__ int s[256];
  int t=threadIdx.x;
  int i=blockIdx.x*256+t;
  s[t]=(i<n)?in[i]:0;
  __syncthreads();
  for(int o=1;o<256;o<<=1){
    int v=(t>=o)?s[t-o]:0;
    __syncthreads();
    s[t]+=v;
    __syncthreads();
  }
  if(i<n) out[i+1]=psum[blockIdx.x]+s[t];
  if(i==0) out[0]=0;
}

__global__ void scatter_edges(const int* __restrict__ eidx, const int* __restrict__ eattr,
                              const int* __restrict__ rowptr, int* __restrict__ cnt,
                              u32* __restrict__ es_pk){
  int e=blockIdx.x*256+threadIdx.x;
  if(e>=NEDGES) return;
  int s=eidx[e], d=eidx[NEDGES+e];
  int pos=rowptr[d]+atomicAdd(&cnt[d],1);
  es_pk[pos]=(u32)s | ((u32)(eattr[2*e]*3+eattr[2*e+1])<<16);
}

__global__ void scatter_batch(const int* __restrict__ batch, const int* __restrict__ browptr,
                              int* __restrict__ bcnt, u16* __restrict__ bnodes){
  int n=blockIdx.x*256+threadIdx.x;
  if(n>=NNODES) return;
  int g=batch[n];
  int pos=browptr[g]+atomicAdd(&bcnt[g],1);
  bnodes[pos]=(u16)n;
}

// ---- aggregate: one WAVE per node row; lane covers 8 cols (16B). combo bank-swizzled. ----
__global__ void agg_kernel(const u16* __restrict__ h, const int* __restrict__ rowptr,
    const u32* __restrict__ es_pk, const float* __restrict__ emb1, const float* __restrict__ emb2,
    u16* __restrict__ agg, int n0, int n1){
  __shared__ float combo[10*DIM];
  for(int i=threadIdx.x;i<10*DIM;i+=256){
    int c=i>>9, d=i&(DIM-1);
    int bt=(c<9)?(c/3):4, bd=(c<9)?(c%3):0;
    combo[c*DIM + ((d&7)<<6) + (d>>3)] = emb1[bt*DIM+d]+emb2[bd*DIM+d];
  }
  __syncthreads();
  int w=threadIdx.x>>6, l=threadIdx.x&63;
  for(int n=n0+blockIdx.x*4+w; n<n1; n+=gridDim.x*4){
    float a[8];
    if(n<NNODES){
      const float* cb=combo+9*DIM;
      h8 hv=*(const h8*)&h[(size_t)n*DIM + l*8];
      #pragma unroll
      for(int j=0;j<8;++j) a[j]=(float)hv[j]+cb[j*64+l];
      int pe=rowptr[n+1];
      for(int p=rowptr[n];p<pe;++p){
        u32 pk=es_pk[p];
        int s=pk&0xFFFF;
        const float* cc=combo+(pk>>16)*DIM;
        h8 sv=*(const h8*)&h[(size_t)s*DIM + l*8];
        #pragma unroll
        for(int j=0;j<8;++j) a[j]+=(float)sv[j]+cc[j*64+l];
      }
    } else {
      #pragma unroll
      for(int j=0;j<8;++j) a[j]=0.f;
    }
    s16x8 ov;
    #pragma unroll
    for(int j=0;j<8;++j) ov[j]=(short)f2h(a[j]);
    *(s16x8*)&agg[(size_t)(n-n0)*DIM + l*8]=ov;
  }
}

// ---- fp16 GEMM: C = act(A[MxK]*B[NxK]^T + bias); optional fused BN-stats (col sum/sumsq) ----
template<int RELU,int STATS>
__global__ __launch_bounds__(256) void gemm_f16(
    const u16* __restrict__ A, int lda,
    const u16* __restrict__ B, int ldb,
    const float* __restrict__ bias,
    u16* __restrict__ C, int ldc, int K,
    float* __restrict__ stats, int rowlim)
{
  __shared__ u16 As[128*64] __attribute__((aligned(16)));
  __shared__ u16 Bs[128*64] __attribute__((aligned(16)));
  __shared__ float sS[128], sQ[128];
  int t=threadIdx.x, w=t>>6, l=t&63;
  if(STATS){ if(t<128) sS[t]=0.f; else sQ[t-128]=0.f; }
  size_t col0=(size_t)blockIdx.x*128, row0=(size_t)blockIdx.y*128;
  int wr=w>>1, wc=w&1;
  int lr=l&15, lk=(l>>4)*8;
  f32x4 acc[4][4]={};
  for(int k0=0;k0<K;k0+=64){
    #pragma unroll
    for(int i=0;i<4;++i){
      int c=i*256+t; int r=c>>3, c8=c&7;
      __builtin_amdgcn_global_load_lds(
        (const __attribute__((address_space(1))) void*)(A+(row0+r)*lda+k0+c8*8),
        (__attribute__((address_space(3))) void*)(As+(size_t)(i*256+(w<<6))*8), 16,0,0);
      __builtin_amdgcn_global_load_lds(
        (const __attribute__((address_space(1))) void*)(B+(col0+r)*ldb+k0+c8*8),
        (__attribute__((address_space(3))) void*)(Bs+(size_t)(i*256+(w<<6))*8), 16,0,0);
    }
    __syncthreads();
    #pragma unroll
    for(int kk=0;kk<2;++kk){
      h8 av[4],bv[4];
      #pragma unroll
      for(int m=0;m<4;++m) av[m]=*(const h8*)(As+(wr*64+m*16+lr)*64+kk*32+lk);
      #pragma unroll
      for(int n=0;n<4;++n) bv[n]=*(const h8*)(Bs+(wc*64+n*16+lr)*64+kk*32+lk);
      #pragma unroll
      for(int m=0;m<4;++m)
        #pragma unroll
        for(int n=0;n<4;++n)
          acc[m][n]=__builtin_amdgcn_mfma_f32_16x16x32_f16(av[m],bv[n],acc[m][n],0,0,0);
    }
    __syncthreads();
  }
  #pragma unroll
  for(int n=0;n<4;++n){
    int col=(int)col0+wc*64+n*16+lr;
    float bcol=bias[col];
    float cs=0.f, cq=0.f;
    #pragma unroll
    for(int m=0;m<4;++m){
      int rowb=(int)row0+wr*64+m*16+((l>>4)*4);
      #pragma unroll
      for(int r=0;r<4;++r){
        float v=acc[m][n][r]+bcol;
        if(RELU) v=fmaxf(v,0.f);
        C[(size_t)(rowb+r)*ldc+col]=f2h(v);
        if(STATS){ if(rowb+r<rowlim){ cs+=v; cq+=v*v; } }
      }
    }
    if(STATS){
      cs+=__shfl_xor(cs,16); cs+=__shfl_xor(cs,32);
      cq+=__shfl_xor(cq,16); cq+=__shfl_xor(cq,32);
      if((l>>4)==0){
        atomicAdd(&sS[wc*64+n*16+lr],cs);
        atomicAdd(&sQ[wc*64+n*16+lr],cq);
      }
    }
  }
  if(STATS){
    __syncthreads();
    if(t<128) atomicAdd(&stats[col0+t], sS[t]);
    else      atomicAdd(&stats[DIM+col0+(t-128)], sQ[t-128]);
  }
}

// ---------------- BN finalize + apply ----------------
__global__ void bn_finalize(float* __restrict__ stats, const float* __restrict__ gamma,
                            const float* __restrict__ beta){
  int d=threadIdx.x;
  float mu=stats[d]*(1.f/NNODES);
  float var=stats[DIM+d]*(1.f/NNODES)-mu*mu;
  float sc=gamma[d]*rsqrtf(var+1e-5f);
  stats[2*DIM+d]=sc;
  stats[3*DIM+d]=beta[d]-mu*sc;
}

__global__ void bn_apply(const u16* __restrict__ h2, const float* __restrict__ stats,
    u16* __restrict__ h, int relu){
  int idx=blockIdx.x*256+threadIdx.x;  // NNODES*64 threads, 8 elems each
  int d0=(idx&63)*8;
  size_t base=(size_t)idx*8;
  h8 v=*(const h8*)&h2[base];
  s16x8 o;
  #pragma unroll
  for(int j=0;j<8;++j){
    int d=d0+j;
    float x=(float)v[j]*stats[2*DIM+d]+stats[3*DIM+d];
    if(relu) x=fmaxf(x,0.f);
    o[j]=(short)f2h(x);
  }
  *(s16x8*)&h[base]=o;
}

// ---------------- graph pooling: one wave per graph ----------------
__global__ void batch_reduce(const u16* __restrict__ h, const int* __restrict__ browptr,
    const u16* __restrict__ bnodes, u16* __restrict__ z){
  int w=threadIdx.x>>6, l=threadIdx.x&63;
  int g=blockIdx.x*4+w;
  if(g>=NGRAPH) return;
  float a[8]={0,0,0,0,0,0,0,0};
  int pe=browptr[g+1];
  for(int p=browptr[g];p<pe;++p){
    int n=bnodes[p];
    h8 v=*(const h8*)&h[(size_t)n*DIM + l*8];
    #pragma unroll
    for(int j=0;j<8;++j) a[j]+=(float)v[j];
  }
  s16x8 o;
  #pragma unroll
  for(int j=0;j<8;++j) o[j]=(short)f2h(a[j]);
  *(s16x8*)&z[(size_t)g*1024 + l*8]=o;
}

// ---------------- last layer: dot(128) + bias ----------------
__global__ void last_kernel(const u16* __restrict__ z2, const float* __restrict__ lw,
    const float* __restrict__ lb, float* __restrict__ out){
  int g=blockIdx.x*4+(threadIdx.x>>6), l=threadIdx.x&63;
  float a=h2f(z2[g*128+l])*lw[l]+h2f(z2[g*128+64+l])*lw[64+l];
  #pragma unroll
  for(int off=32;off;off>>=1) a+=__shfl_down(a,off,64);
  if(l==0) out[g]=a+lb[0];
}

extern "C" void kernel_launch(void* const* d_in, const int* in_sizes, int n_in,
                              void* d_out, int out_size, void* d_ws, size_t ws_size,
                              hipStream_t stream){
  (void)in_sizes; (void)n_in; (void)out_size;
  const float* solute_x =(const float*)d_in[0];
  const float* solvent_x=(const float*)d_in[1];
  const int*   eidx     =(const int*)d_in[2];
  const int*   eattr    =(const int*)d_in[3];
  const int*   batch    =(const int*)d_in[4];
  const float* xembW=(const float*)d_in[5];
  const float* xembB=(const float*)d_in[6];
  const float* m1W=(const float*)d_in[7];
  const float* m1b=(const float*)d_in[8];
  const float* m2W=(const float*)d_in[9];
  const float* m2b=(const float*)d_in[10];
  const float* ee1=(const float*)d_in[11];
  const float* ee2=(const float*)d_in[12];
  const float* gam=(const float*)d_in[13];
  const float* bet=(const float*)d_in[14];
  const float* sW1=(const float*)d_in[15];
  const float* sb1=(const float*)d_in[16];
  const float* sW2=(const float*)d_in[17];
  const float* sb2=(const float*)d_in[18];
  const float* oW0=(const float*)d_in[19];
  const float* ob0=(const float*)d_in[20];
  const float* oW1=(const float*)d_in[21];
  const float* ob1=(const float*)d_in[22];
  const float* oW2=(const float*)d_in[23];
  const float* ob2=(const float*)d_in[24];
  const float* lW =(const float*)d_in[25];
  const float* lb =(const float*)d_in[26];
  float* out=(float*)d_out;

  char* p=(char*)d_ws; size_t off=0;
  auto alloc=[&](size_t b)->void*{ void* q=p+off; off+=(b+255)&~(size_t)255; return q; };
  u16* h_f   =(u16*)alloc((size_t)NPAD*DIM*2);
  u16* h2_f  =(u16*)alloc((size_t)NPAD*DIM*2);
  u16* W1t =(u16*)alloc((size_t)NLAYER*1024*512*2);
  u16* W2t =(u16*)alloc((size_t)NLAYER*512*1024*2);
  u16* sW2t=(u16*)alloc((size_t)512*512*2);
  u16* oW0t=(u16*)alloc((size_t)512*1024*2);
  u16* oW1t=(u16*)alloc((size_t)256*512*2);
  u16* oW2t=(u16*)alloc((size_t)128*256*2);
  u16* s1 =(u16*)alloc((size_t)NGRAPH*512*2);
  u16* z  =(u16*)alloc((size_t)NGRAPH*1024*2);
  u16* z0 =(u16*)alloc((size_t)NGRAPH*512*2);
  u16* z1 =(u16*)alloc((size_t)NGRAPH*256*2);
  u16* z2 =(u16*)alloc((size_t)NGRAPH*128*2);
  float* stats=(float*)alloc(4*DIM*4);
  int* rowptr =(int*)alloc((size_t)(NNODES+1)*4);
  int* degcnt =(int*)alloc((size_t)NNODES*4);
  u32* es_pk  =(u32*)alloc((size_t)NEDGES*4);
  int* bdeg   =(int*)alloc((size_t)NGRAPH*4);
  int* browptr=(int*)alloc((size_t)(NGRAPH+1)*4);
  int* bcnt   =(int*)alloc((size_t)NGRAPH*4);
  u16* bnodes =(u16*)alloc((size_t)NNODES*2);

  // chunk buffers sized from remaining workspace
  const size_t per_chb=(size_t)128*512*2 + (size_t)128*1024*2;  // agg + t per 128-row block
  size_t left = ws_size>off+4096 ? ws_size-off-4096 : 0;
  int chb=(int)(left/per_chb);
  if(chb<1) return;            // cannot fit: launch nothing (diagnostic)
  if(chb>NBLK) chb=NBLK;
  u16* agg_c=(u16*)alloc((size_t)chb*128*512*2);
  u16* t_c  =(u16*)alloc((size_t)chb*128*1024*2);

  // ---- weight transposes (fp32 -> fp16 NxK) ----
  for(int l=0;l<NLAYER;++l){
    transpose_bt<<<dim3(32,16),256,0,stream>>>(m1W+(size_t)l*512*1024, W1t+(size_t)l*1024*512, 512,1024);
    transpose_bt<<<dim3(16,32),256,0,stream>>>(m2W+(size_t)l*1024*512, W2t+(size_t)l*512*1024, 1024,512);
  }
  transpose_bt<<<dim3(16,16),256,0,stream>>>(sW2, sW2t, 512,512);
  transpose_bt<<<dim3(16,32),256,0,stream>>>(oW0, oW0t, 1024,512);
  transpose_bt<<<dim3(8,16),256,0,stream>>>(oW1, oW1t, 512,256);
  transpose_bt<<<dim3(4,8),256,0,stream>>>(oW2, oW2t, 256,128);

  // ---- embed ----
  dense40<<<2048,256,0,stream>>>(solute_x, xembW, xembB, h_f, NNODES, NPAD);

  // ---- edge CSR (parallel scan) ----
  hipMemsetAsync(degcnt,0,(size_t)NNODES*4,stream);
  hist_kernel<<<(NEDGES+255)/256,256,0,stream>>>(eidx+NEDGES, degcnt, NEDGES);
  {
    int nb=(NNODES+255)/256;   // 235
    block_sums<<<nb,256,0,stream>>>(degcnt, bdeg, NNODES);
    scan_partials<<<1,256,0,stream>>>(bdeg, nb);
    scan_write<<<nb,256,0,stream>>>(degcnt, bdeg, rowptr, NNODES);
  }
  hipMemsetAsync(degcnt,0,(size_t)NNODES*4,stream);
  scatter_edges<<<(NEDGES+255)/256,256,0,stream>>>(eidx, eattr, rowptr, degcnt, es_pk);

  // ---- batch CSR ----
  hipMemsetAsync(bdeg,0,(size_t)NGRAPH*4,stream);
  hist_kernel<<<(NNODES+255)/256,256,0,stream>>>(batch, bdeg, NNODES);
  {
    int nb=(NGRAPH+255)/256;   // 8
    block_sums<<<nb,256,0,stream>>>(bdeg, bcnt, NGRAPH);
    scan_partials<<<1,256,0,stream>>>(bcnt, nb);
    scan_write<<<nb,256,0,stream>>>(bdeg, bcnt, browptr, NGRAPH);
  }
  hipMemsetAsync(bcnt,0,(size_t)NGRAPH*4,stream);
  scatter_batch<<<(NNODES+255)/256,256,0,stream>>>(batch, browptr, bcnt, bnodes);

  // ---- GNN layers ----
  for(int l=0;l<NLAYER;++l){
    const float* e1=ee1+(size_t)l*6*DIM;
    const float* e2=ee2+(size_t)l*3*DIM;
    hipMemsetAsync(stats,0,2*DIM*4,stream);
    for(int b0=0;b0<NBLK;b0+=chb){
      int nb=NBLK-b0; if(nb>chb) nb=chb;
      int n0=b0*128, rows=nb*128;
      agg_kernel<<<2048,256,0,stream>>>(h_f, rowptr, es_pk, e1, e2, agg_c, n0, n0+rows);
      gemm_f16<1,0><<<dim3(8,nb),256,0,stream>>>(agg_c, 512, W1t+(size_t)l*1024*512, 512,
          m1b+(size_t)l*1024, t_c, 1024, 512, nullptr, 1<<30);
      gemm_f16<0,1><<<dim3(4,nb),256,0,stream>>>(t_c, 1024, W2t+(size_t)l*512*1024, 1024,
          m2b+(size_t)l*512, h2_f+(size_t)n0*DIM, 512, 1024, stats, NNODES-n0);
    }
    bn_finalize<<<1,512,0,stream>>>(stats, gam+(size_t)l*DIM, bet+(size_t)l*DIM);
    bn_apply<<<(NNODES*64)/256,256,0,stream>>>(h2_f, stats, h_f, (l<NLAYER-1)?1:0);
  }

  // ---- pooling + solvent + readout ----
  batch_reduce<<<512,256,0,stream>>>(h_f, browptr, bnodes, z);
  dense40<<<2048,256,0,stream>>>(solvent_x, sW1, sb1, s1, NGRAPH, NGRAPH);
  gemm_f16<0,0><<<dim3(4,16),256,0,stream>>>(s1, 512, sW2t, 512, sb2, z+512, 1024, 512, nullptr, 1<<30);
  gemm_f16<1,0><<<dim3(4,16),256,0,stream>>>(z, 1024, oW0t, 1024, ob0, z0, 512, 1024, nullptr, 1<<30);
  gemm_f16<1,0><<<dim3(2,16),256,0,stream>>>(z0, 512, oW1t, 512, ob1, z1, 256, 512, nullptr, 1<<30);
  gemm_f16<1,0><<<dim3(1,16),256,0,stream>>>(z1, 256, oW2t, 256, ob2, z2, 128, 256, nullptr, 1<<30);
  last_kernel<<<NGRAPH/4,256,0,stream>>>(z2, lW, lb, out);
}